// Round 7
// baseline (293.582 us; speedup 1.0000x reference)
//
#include <hip/hip_runtime.h>

typedef float floatx4 __attribute__((ext_vector_type(4)));
typedef float floatx16 __attribute__((ext_vector_type(16)));
typedef short short8 __attribute__((ext_vector_type(8)));

#define HIDDEN 2048
#define NH 16
#define NKV 4
#define HD 128
#define NB 2
#define SEQ 2048
#define MT (NB * SEQ)  // 4096
#define NQKV 3072      // fused projection width: 2048 Q + 512 K + 512 V

__device__ __forceinline__ unsigned short f2bf(float x) {
  union { float f; unsigned u; } v; v.f = x;
  unsigned r = v.u + 0x7FFFu + ((v.u >> 16) & 1u);  // RNE
  return (unsigned short)(r >> 16);
}

__device__ __forceinline__ unsigned int cvt_pk_bf16(float lo, float hi) {
  unsigned int r;
  asm("v_cvt_pk_bf16_f32 %0, %1, %2" : "=v"(r) : "v"(lo), "v"(hi));
  return r;
}

// ------- fused prep: contiguous fp32->bf16 cast + weight transpose/cast -------
__global__ void prep_kernel(const float* __restrict__ hidden,
                            unsigned short* __restrict__ hb,
                            const float* __restrict__ Wq,
                            const float* __restrict__ Wk,
                            const float* __restrict__ Wv,
                            const float* __restrict__ Wo,
                            unsigned short* __restrict__ wqkvt,
                            unsigned short* __restrict__ wot) {
  const int bid = blockIdx.x;
  if (bid < 8192) {
    int i = bid * 256 + threadIdx.x;
    float4 v = ((const float4*)hidden)[i];
    ushort4 o;
    o.x = f2bf(v.x); o.y = f2bf(v.y); o.z = f2bf(v.z); o.w = f2bf(v.w);
    ((ushort4*)hb)[i] = o;
    return;
  }
  __shared__ float tile[32][33];
  const int wb = bid - 8192;
  const int z = wb >> 12;            // 0..2
  const int rem = wb & 4095;
  const int nt = (rem & 63) * 32;
  const int k0 = (rem >> 6) * 32;
  const float* src;
  unsigned short* dst;
  int Nd, scol0, drow0;
  if (z == 0) {
    src = Wq; Nd = 2048; scol0 = nt; drow0 = nt; dst = wqkvt;
  } else if (z == 1) {
    src = Wo; Nd = 2048; scol0 = nt; drow0 = nt; dst = wot;
  } else {
    if (nt >= 1024) return;          // block-uniform
    Nd = 512; dst = wqkvt; drow0 = 2048 + nt;
    if (nt < 512) { src = Wk; scol0 = nt; }
    else          { src = Wv; scol0 = nt - 512; }
  }
  const int tx = threadIdx.x & 31, ty = threadIdx.x >> 5;
  for (int i = 0; i < 32; i += 8)
    tile[ty + i][tx] = src[(size_t)(k0 + ty + i) * Nd + scol0 + tx];
  __syncthreads();
  for (int i = 0; i < 32; i += 8)
    dst[(size_t)(drow0 + ty + i) * HIDDEN + k0 + tx] = f2bf(tile[tx][ty + i]);
}

// ------- O-proj: C[M][N] fp32 = A @ Bt^T, 32x32x16 MFMA (verified round-6) ----
__global__ __launch_bounds__(256, 3)
void gemm_bf16_kernel(const unsigned short* __restrict__ A,
                      const unsigned short* __restrict__ Bt,
                      float* __restrict__ C, int M, int N, int K) {
  __shared__ unsigned short As[128 * 64];
  __shared__ unsigned short Bs[128 * 64];
  const int tid = threadIdx.x;
  const int wave = tid >> 6, lane = tid & 63;
  const int c5 = lane & 31, h5 = lane >> 5;
  const int m0 = blockIdx.x * 128, n0 = blockIdx.y * 128;
  const int wm = (wave >> 1) * 64, wn = (wave & 1) * 64;
  const int srow8 = lane >> 3;
  const int scol = (((lane & 7) ^ srow8) * 8);

  floatx16 acc[2][2] = {};

  for (int kt = 0; kt < K; kt += 64) {
    __syncthreads();
#pragma unroll
    for (int t = 0; t < 4; ++t) {
      int row = t * 32 + wave * 8 + srow8;
      __builtin_amdgcn_global_load_lds(
          (const __attribute__((address_space(1))) unsigned int*)&A[(size_t)(m0 + row) * K + kt + scol],
          (__attribute__((address_space(3))) unsigned int*)&As[(t * 32 + wave * 8) * 64],
          16, 0, 0);
    }
#pragma unroll
    for (int t = 0; t < 4; ++t) {
      int row = t * 32 + wave * 8 + srow8;
      __builtin_amdgcn_global_load_lds(
          (const __attribute__((address_space(1))) unsigned int*)&Bt[(size_t)(n0 + row) * K + kt + scol],
          (__attribute__((address_space(3))) unsigned int*)&Bs[(t * 32 + wave * 8) * 64],
          16, 0, 0);
    }
    __syncthreads();
#pragma unroll
    for (int ks = 0; ks < 4; ++ks) {
      const int ck = ((2 * ks + h5) ^ (c5 & 7)) * 8;
      short8 a0 = *(const short8*)&As[(wm + c5) * 64 + ck];
      short8 a1 = *(const short8*)&As[(wm + 32 + c5) * 64 + ck];
      short8 b0 = *(const short8*)&Bs[(wn + c5) * 64 + ck];
      short8 b1 = *(const short8*)&Bs[(wn + 32 + c5) * 64 + ck];
      acc[0][0] = __builtin_amdgcn_mfma_f32_32x32x16_bf16(a0, b0, acc[0][0], 0, 0, 0);
      acc[0][1] = __builtin_amdgcn_mfma_f32_32x32x16_bf16(a0, b1, acc[0][1], 0, 0, 0);
      acc[1][0] = __builtin_amdgcn_mfma_f32_32x32x16_bf16(a1, b0, acc[1][0], 0, 0, 0);
      acc[1][1] = __builtin_amdgcn_mfma_f32_32x32x16_bf16(a1, b1, acc[1][1], 0, 0, 0);
    }
  }
#pragma unroll
  for (int bi = 0; bi < 2; ++bi)
#pragma unroll
    for (int bj = 0; bj < 2; ++bj) {
      const int colg = n0 + wn + bj * 32 + c5;
#pragma unroll
      for (int reg = 0; reg < 16; ++reg) {
        const int rowg = m0 + wm + bi * 32 + (reg & 3) + 4 * h5 + 8 * (reg >> 2);
        C[(size_t)rowg * N + colg] = acc[bi][bj][reg];
      }
    }
}

// ------- QKV GEMM with fused RMSNorm+RoPE (Q/K) and V-transpose epilogue -------
// (unchanged from verified round-4: qkv ~70us, conflicts 164K)
__global__ __launch_bounds__(256, 3)
void gemm_qkv_kernel(const unsigned short* __restrict__ A,    // hb [MT][2048]
                     const unsigned short* __restrict__ Bt,   // wqkvt [3072][2048]
                     const float* __restrict__ qw,
                     const float* __restrict__ kw,
                     const float* __restrict__ cosb,
                     const float* __restrict__ sinb,
                     unsigned short* __restrict__ Qb,   // [NB][NH][SEQ][HD]
                     unsigned short* __restrict__ Kbb,  // [NB][NKV][SEQ][HD]
                     unsigned short* __restrict__ Vt) { // [NB][NKV][HD][SEQ]
  __shared__ __align__(16) char sh[32768];
  unsigned short* As = (unsigned short*)sh;              // [128][64] (16 KB)
  unsigned short* Bs = (unsigned short*)(sh + 16384);    // [128][64] (16 KB)
  float* pscr = (float*)sh;                              // [4][64][20] (20 KB)
  float* pssq = (float*)(sh + 20480);                    // [2][128]   (1 KB)
  const int tid = threadIdx.x;
  const int wave = tid >> 6, lane = tid & 63;
  const int quad = lane >> 4, l16 = lane & 15;
  const int nwg = gridDim.x * gridDim.y;
  const int orig = blockIdx.y * gridDim.x + blockIdx.x;
  const int lin = (orig & 7) * (nwg >> 3) + (orig >> 3);
  const int bx = lin % gridDim.x, by = lin / gridDim.x;
  const int m0 = bx * 128, n0 = by * 128;
  const int wm = (wave >> 1) * 64, wn = (wave & 1) * 64;
  const int srow8 = lane >> 3;
  const int scol = (((lane & 7) ^ srow8) * 8);
  const int rsw = (l16 & 7);

  floatx4 acc[4][4] = {};

  for (int kt = 0; kt < HIDDEN; kt += 64) {
    __syncthreads();
#pragma unroll
    for (int t = 0; t < 4; ++t) {
      int row = t * 32 + wave * 8 + srow8;
      __builtin_amdgcn_global_load_lds(
          (const __attribute__((address_space(1))) unsigned int*)&A[(size_t)(m0 + row) * HIDDEN + kt + scol],
          (__attribute__((address_space(3))) unsigned int*)&As[(t * 32 + wave * 8) * 64],
          16, 0, 0);
    }
#pragma unroll
    for (int t = 0; t < 4; ++t) {
      int row = t * 32 + wave * 8 + srow8;
      __builtin_amdgcn_global_load_lds(
          (const __attribute__((address_space(1))) unsigned int*)&Bt[(size_t)(n0 + row) * HIDDEN + kt + scol],
          (__attribute__((address_space(3))) unsigned int*)&Bs[(t * 32 + wave * 8) * 64],
          16, 0, 0);
    }
    __syncthreads();
#pragma unroll
    for (int kk = 0; kk < 2; ++kk) {
      const int ck = ((kk * 4 + quad) ^ rsw) * 8;
      short8 af[4], bf[4];
#pragma unroll
      for (int i = 0; i < 4; i++)
        af[i] = *(const short8*)&As[(wm + i * 16 + l16) * 64 + ck];
#pragma unroll
      for (int j = 0; j < 4; j++)
        bf[j] = *(const short8*)&Bs[(wn + j * 16 + l16) * 64 + ck];
#pragma unroll
      for (int i = 0; i < 4; i++)
#pragma unroll
        for (int j = 0; j < 4; j++)
          acc[i][j] = __builtin_amdgcn_mfma_f32_16x16x32_bf16(af[i], bf[j], acc[i][j], 0, 0, 0);
    }
  }

  const int head = n0 >> 7;
  if (head >= NH + NKV) {
    const int kv = head - (NH + NKV);
#pragma unroll
    for (int i = 0; i < 4; ++i) {
      int m = m0 + wm + i * 16 + quad * 4;
      int b = m >> 11, sbase = m & (SEQ - 1);
#pragma unroll
      for (int j = 0; j < 4; ++j) {
        int d = wn + j * 16 + l16;
        ushort4 pk;
        pk.x = f2bf(acc[i][j][0]); pk.y = f2bf(acc[i][j][1]);
        pk.z = f2bf(acc[i][j][2]); pk.w = f2bf(acc[i][j][3]);
        *(ushort4*)&Vt[((size_t)(b * NKV + kv) * HD + d) * SEQ + sbase] = pk;
      }
    }
    return;  // head is block-uniform: no barrier divergence
  }

  __syncthreads();  // all waves done reading As/Bs before pscr/pssq reuse the LDS
  const float* w = (head < NH) ? qw : kw;
  float wown[4], wpar[4];
#pragma unroll
  for (int j = 0; j < 4; ++j) {
    wown[j] = w[wn + j * 16 + l16];
    wpar[j] = w[(wn ^ 64) + j * 16 + l16];
  }
#pragma unroll
  for (int i = 0; i < 4; ++i) {
    float sq[4];
#pragma unroll
    for (int r = 0; r < 4; ++r) {
      float s2 = acc[i][0][r] * acc[i][0][r] + acc[i][1][r] * acc[i][1][r] +
                 acc[i][2][r] * acc[i][2][r] + acc[i][3][r] * acc[i][3][r];
#pragma unroll
      for (int off = 1; off < 16; off <<= 1) s2 += __shfl_xor(s2, off, 64);
      sq[r] = s2;
    }
    if (l16 == 0)
      *(float4*)&pssq[(wn >> 6) * 128 + wm + i * 16 + quad * 4] = make_float4(sq[0], sq[1], sq[2], sq[3]);
#pragma unroll
    for (int j = 0; j < 4; ++j)
      *(float4*)&pscr[(wave * 64 + j * 16 + l16) * 20 + quad * 4] = *(float4*)&acc[i][j];
    __syncthreads();
    float4 oss = *(const float4*)&pssq[((wn >> 6) ^ 1) * 128 + wm + i * 16 + quad * 4];
    float rr[4];
    rr[0] = rsqrtf((sq[0] + oss.x) * (1.0f / 128.0f) + 1e-6f);
    rr[1] = rsqrtf((sq[1] + oss.y) * (1.0f / 128.0f) + 1e-6f);
    rr[2] = rsqrtf((sq[2] + oss.z) * (1.0f / 128.0f) + 1e-6f);
    rr[3] = rsqrtf((sq[3] + oss.w) * (1.0f / 128.0f) + 1e-6f);
    int mbase = m0 + wm + i * 16 + quad * 4;
    int b = mbase >> 11, sbase = mbase & (SEQ - 1);
#pragma unroll
    for (int j = 0; j < 4; ++j) {
      float4 par = *(const float4*)&pscr[((wave ^ 1) * 64 + j * 16 + l16) * 20 + quad * 4];
      float pr[4] = {par.x, par.y, par.z, par.w};
      int d = wn + j * 16 + l16;
      unsigned short* dst = (head < NH)
          ? Qb + ((size_t)(b * NH + head) * SEQ + sbase) * HD + d
          : Kbb + ((size_t)(b * NKV + (head - NH)) * SEQ + sbase) * HD + d;
#pragma unroll
      for (int r = 0; r < 4; ++r) {
        int s = sbase + r;
        float c = cosb[s * HD + d], sn = sinb[s * HD + d];
        float xo = acc[i][j][r] * rr[r] * wown[j];
        float xp = pr[r] * rr[r] * wpar[j];
        float out = (wn == 0) ? (xo * c - xp * sn) : (xo * c + xp * sn);
        dst[(size_t)r * HD] = f2bf(out);
      }
    }
    __syncthreads();  // pscr/pssq reused next i
  }
}

// ------- flash attention: Q-tile = 128 rows (two 16-col blocks per wave) -------
// Same verified K/V staging, swizzle, kv-relabel, softmax structure as round-4;
// each staged K/V tile now feeds 2 q-column blocks -> half the iterations,
// half the staging/barrier/LDS-read overhead per unit work. T5 setprio on MFMA.
__device__ __forceinline__ void stage_rows(const unsigned short* gbase, int rowstride,
                                           unsigned short* lds, int wave, int quad,
                                           int s_cx, int s_hb) {
#pragma unroll
  for (int i = 0; i < 8; ++i) {
    const int row = i * 16 + wave * 4 + quad;                     // row&3 == quad
    const int sck = s_cx ^ (((2 * i + s_hb) & 3) << 2);           // chunk ^ f(row)
    __builtin_amdgcn_global_load_lds(
        (const __attribute__((address_space(1))) unsigned int*)(gbase + (size_t)row * rowstride + sck * 8),
        (__attribute__((address_space(3))) unsigned int*)(lds + (i * 4 + wave) * 512),
        16, 0, 0);
  }
}

__global__ __launch_bounds__(256, 2)
void attn_kernel(const unsigned short* __restrict__ Q,   // [NB][NH][SEQ][HD]
                 const unsigned short* __restrict__ Kb,  // [NB][NKV][SEQ][HD]
                 const unsigned short* __restrict__ Vt,  // [NB][NKV][HD][SEQ]
                 unsigned short* __restrict__ O) {       // [MT][NH*HD]
  __shared__ __align__(16) unsigned short KVs[2][128 * 128];  // 2 x 32 KiB
  const int tid = threadIdx.x;
  const int wave = tid >> 6, lane = tid & 63;
  const int quad = lane >> 4, l16 = lane & 15;
  const int l3 = l16 & 3, s3 = l16 >> 3, s2 = (l16 >> 2) & 1;
  const int x = blockIdx.x;
  // qt pairing: blocks x and x+256 (same CU slot under round-robin) get
  // qt = 15-k and k -> balanced work; 16 qt x 32 bh = 512 blocks.
  const int qt = (x < 256) ? (15 - (x >> 5)) : ((x - 256) >> 5);
  const int bh = x & 31;
  const int b = bh >> 4, h = bh & 15, kvh = h >> 2;

  const int s_cx = (lane & 15) ^ quad;                  // staging chunk ^ (row&3)
  const int s_hb = wave >> 1;                           // (4*wave+quad)>>3
  const int krbase = 16 * s3 + 8 * s2 + l3;             // permuted K-row base
  const int f_k = l3 | ((2 * s3 + s2) << 2);            // f(krow), j-independent
  const int kvqb = 16 * (quad >> 1) + 8 * (quad & 1);   // kv label base per quad
  const int qsw = (lane & 48) | (quad << 2);            // col->row state shfl base
  const float CS = 0.08838834764831845f;                // 1/sqrt(128)

  const unsigned short* Kg0 = Kb + (size_t)((b * NKV + kvh) * SEQ) * HD;
  const unsigned short* Vg0 = Vt + (size_t)((b * NKV + kvh) * HD) * SEQ;

  const int q0 = qt * 128;
  const int nkt = qt + 1;

  // Q fragments: wave owns rows q0 + wave*32 .. +32, split in c-blocks of 16
  const unsigned short* Qg = Q + (size_t)((b * NH + h) * SEQ + q0) * HD;
  short8 qf[2][4];
#pragma unroll
  for (int c = 0; c < 2; ++c)
#pragma unroll
    for (int ks = 0; ks < 4; ++ks)
      qf[c][ks] = *(const short8*)&Qg[(size_t)(wave * 32 + c * 16 + l16) * HD + ks * 32 + quad * 8];

  floatx4 oacc[2][8] = {};
  float mrow[2] = {-1e30f, -1e30f};
  float lrow[2] = {0.f, 0.f};
  const int qg0 = q0 + wave * 32 + l16;                 // c=0 lane q; c=1 adds 16

  int p = 0;
  stage_rows(Kg0, 128, KVs[p], wave, quad, s_cx, s_hb);          // K tile 0
  __syncthreads();

  for (int kt = 0; kt < nkt; ++kt) {
    const unsigned short* KVp = KVs[p];
    // ---- S^T = K @ Q^T, both q-column blocks share each K fragment ----
    floatx4 sc[2][8] = {};
    __builtin_amdgcn_s_setprio(1);
#pragma unroll
    for (int ks = 0; ks < 4; ++ks) {
      const int cko = ((ks * 4 + quad) ^ f_k) * 8;
#pragma unroll
      for (int j = 0; j < 8; ++j) {
        const short8 kf = *(const short8*)&KVp[(krbase + 32 * (j >> 1) + 4 * (j & 1)) * 128 + cko];
        sc[0][j] = __builtin_amdgcn_mfma_f32_16x16x32_bf16(kf, qf[0][ks], sc[0][j], 0, 0, 0);
        sc[1][j] = __builtin_amdgcn_mfma_f32_16x16x32_bf16(kf, qf[1][ks], sc[1][j], 0, 0, 0);
      }
    }
    __builtin_amdgcn_s_setprio(0);
    __syncthreads();  // all K reads done; prev PV reads done
    // V_kt overwrites current buffer; prefetch K_{kt+1} into the other one.
    stage_rows(Vg0 + kt * 128, SEQ, KVs[p], wave, quad, s_cx, s_hb);
    if (kt + 1 < nkt)
      stage_rows(Kg0 + (size_t)(kt + 1) * 128 * HD, 128, KVs[p ^ 1], wave, quad, s_cx, s_hb);

    // ---- causal mask (last tile only) ----
    if (kt == nkt - 1) {
#pragma unroll
      for (int c = 0; c < 2; ++c) {
        const int qgc = qg0 + c * 16;
#pragma unroll
        for (int j = 0; j < 8; ++j) {
          const int kvj = kt * 128 + 32 * (j >> 1) + 4 * (j & 1) + kvqb;
#pragma unroll
          for (int r = 0; r < 4; ++r)
            if (kvj + r > qgc) sc[c][j][r] = -1e30f;
        }
      }
    }
    // ---- online softmax per c-block; pack P; sc[c] dies before PV ----
    unsigned int pk[2][8][2];
#pragma unroll
    for (int c = 0; c < 2; ++c) {
      float mx = -1e30f;
#pragma unroll
      for (int j = 0; j < 8; ++j)
        mx = fmaxf(mx, fmaxf(fmaxf(sc[c][j][0], sc[c][j][1]), fmaxf(sc[c][j][2], sc[c][j][3])));
      mx = fmaxf(mx, __shfl_xor(mx, 16, 64));
      mx = fmaxf(mx, __shfl_xor(mx, 32, 64));
      if (!__all(mx <= mrow[c] + 62.0f)) {  // defer-max
        const float mnew = fmaxf(mrow[c], mx);
        const float al = __expf((mrow[c] - mnew) * CS);
        mrow[c] = mnew;
        lrow[c] *= al;
#pragma unroll
        for (int r = 0; r < 4; ++r) {
          const float ar = __shfl(al, qsw + r, 64);     // col-state -> row-space
#pragma unroll
          for (int t = 0; t < 8; ++t) oacc[c][t][r] *= ar;
        }
      }
      const float mc = mrow[c] * CS;
      float rs = 0.f;
#pragma unroll
      for (int j = 0; j < 8; ++j)
#pragma unroll
        for (int r = 0; r < 4; ++r) {
          const float pe = __expf(sc[c][j][r] * CS - mc);
          sc[c][j][r] = pe;
          rs += pe;
        }
      rs += __shfl_xor(rs, 16, 64);
      rs += __shfl_xor(rs, 32, 64);
      lrow[c] += rs;
#pragma unroll
      for (int j = 0; j < 8; ++j) {
        pk[c][j][0] = cvt_pk_bf16(sc[c][j][0], sc[c][j][1]);
        pk[c][j][1] = cvt_pk_bf16(sc[c][j][2], sc[c][j][3]);
      }
    }
    __syncthreads();  // V ready (drains staging loads)
    // ---- O += P @ V, both c-blocks share each V fragment ----
    __builtin_amdgcn_s_setprio(1);
#pragma unroll
    for (int ks = 0; ks < 4; ++ks) {
      union { unsigned int u[4]; short8 s; } a0, a1;
      a0.u[0] = pk[0][2 * ks][0];     a0.u[1] = pk[0][2 * ks][1];
      a0.u[2] = pk[0][2 * ks + 1][0]; a0.u[3] = pk[0][2 * ks + 1][1];
      a1.u[0] = pk[1][2 * ks][0];     a1.u[1] = pk[1][2 * ks][1];
      a1.u[2] = pk[1][2 * ks + 1][0]; a1.u[3] = pk[1][2 * ks + 1][1];
#pragma unroll
      for (int t = 0; t < 8; ++t) {
        const int fv = l3 | (((2 * t + s3) & 3) << 2);
        const short8 vf = *(const short8*)&KVp[(t * 16 + l16) * 128 + (((ks * 4 + quad) ^ fv) * 8)];
        oacc[0][t] = __builtin_amdgcn_mfma_f32_16x16x32_bf16(a0.s, vf, oacc[0][t], 0, 0, 0);
        oacc[1][t] = __builtin_amdgcn_mfma_f32_16x16x32_bf16(a1.s, vf, oacc[1][t], 0, 0, 0);
      }
    }
    __builtin_amdgcn_s_setprio(0);
    p ^= 1;
  }
  // ---- epilogue ----
#pragma unroll
  for (int c = 0; c < 2; ++c) {
    float li[4];
#pragma unroll
    for (int r = 0; r < 4; ++r) li[r] = 1.0f / __shfl(lrow[c], qsw + r, 64);
#pragma unroll
    for (int t = 0; t < 8; ++t) {
      const int col = h * HD + t * 16 + l16;
#pragma unroll
      for (int r = 0; r < 4; ++r) {
        const int row = q0 + wave * 32 + c * 16 + quad * 4 + r;
        O[(size_t)(b * SEQ + row) * (NH * HD) + col] = f2bf(oacc[c][t][r] * li[r]);
      }
    }
  }
}

extern "C" void kernel_launch(void* const* d_in, const int* in_sizes, int n_in,
                              void* d_out, int out_size, void* d_ws, size_t ws_size,
                              hipStream_t stream) {
  const float* hidden = (const float*)d_in[0];
  const float* cosb   = (const float*)d_in[1];
  const float* sinb   = (const float*)d_in[2];
  const float* Wq     = (const float*)d_in[3];
  const float* Wk     = (const float*)d_in[4];
  const float* Wv     = (const float*)d_in[5];
  const float* Wo     = (const float*)d_in[6];
  const float* qw     = (const float*)d_in[7];
  const float* kw     = (const float*)d_in[8];
  (void)in_sizes; (void)n_in; (void)out_size; (void)ws_size;

  char* ws = (char*)d_ws;
  size_t off = 0;
  auto alloc = [&](size_t n) { char* p = ws + off; off += (n + 255) & ~(size_t)255; return p; };

  unsigned short* hb    = (unsigned short*)alloc((size_t)MT * HIDDEN * 2);   // (16 MB)
  unsigned short* wqkvt = (unsigned short*)alloc((size_t)NQKV * HIDDEN * 2); // (12 MB)
  unsigned short* wot   = (unsigned short*)alloc((size_t)2048 * 2048 * 2);   // (8 MB)
  unsigned short* Qb  = (unsigned short*)alloc((size_t)MT * 2048 * 2);  // (16 MB)
  unsigned short* Kbb = (unsigned short*)alloc((size_t)MT * 512 * 2);   // (4 MB)
  unsigned short* Vtb = (unsigned short*)alloc((size_t)MT * 512 * 2);   // (4 MB)
  unsigned short* Ob  = (unsigned short*)alloc((size_t)MT * 2048 * 2);  // (16 MB)

  // fused prep: cast (8192 blocks) + weight transpose (12288 blocks)
  prep_kernel<<<20480, 256, 0, stream>>>(hidden, hb, Wq, Wk, Wv, Wo, wqkvt, wot);

  // fused QKV projection + norm/rope/V-transpose epilogue: grid 32x24 = 768 blocks
  gemm_qkv_kernel<<<dim3(MT / 128, NQKV / 128), 256, 0, stream>>>(
      hb, wqkvt, qw, kw, cosb, sinb, Qb, Kbb, Vtb);

  // Q-tile=128: 16 q-tiles x 32 bh = 512 blocks, qt paired (15-k, k)
  attn_kernel<<<512, 256, 0, stream>>>(Qb, Kbb, Vtb, Ob);

  // O-projection: 32x32x16 MFMA
  gemm_bf16_kernel<<<dim3(MT / 128, 16), 256, 0, stream>>>(Ob, wot, (float*)d_out, MT, 2048, 2048);
}

// Round 8
// 291.294 us; speedup vs baseline: 1.0079x; 1.0079x over previous
//
#include <hip/hip_runtime.h>

typedef float floatx4 __attribute__((ext_vector_type(4)));
typedef float floatx16 __attribute__((ext_vector_type(16)));
typedef short short8 __attribute__((ext_vector_type(8)));

#define HIDDEN 2048
#define NH 16
#define NKV 4
#define HD 128
#define NB 2
#define SEQ 2048
#define MT (NB * SEQ)  // 4096
#define NQKV 3072      // fused projection width: 2048 Q + 512 K + 512 V

__device__ __forceinline__ unsigned short f2bf(float x) {
  union { float f; unsigned u; } v; v.f = x;
  unsigned r = v.u + 0x7FFFu + ((v.u >> 16) & 1u);  // RNE
  return (unsigned short)(r >> 16);
}

__device__ __forceinline__ unsigned int cvt_pk_bf16(float lo, float hi) {
  unsigned int r;
  asm("v_cvt_pk_bf16_f32 %0, %1, %2" : "=v"(r) : "v"(lo), "v"(hi));
  return r;
}

// ------- fused prep: contiguous fp32->bf16 cast + weight transpose/cast -------
__global__ void prep_kernel(const float* __restrict__ hidden,
                            unsigned short* __restrict__ hb,
                            const float* __restrict__ Wq,
                            const float* __restrict__ Wk,
                            const float* __restrict__ Wv,
                            const float* __restrict__ Wo,
                            unsigned short* __restrict__ wqkvt,
                            unsigned short* __restrict__ wot) {
  const int bid = blockIdx.x;
  if (bid < 8192) {
    int i = bid * 256 + threadIdx.x;
    float4 v = ((const float4*)hidden)[i];
    ushort4 o;
    o.x = f2bf(v.x); o.y = f2bf(v.y); o.z = f2bf(v.z); o.w = f2bf(v.w);
    ((ushort4*)hb)[i] = o;
    return;
  }
  __shared__ float tile[32][33];
  const int wb = bid - 8192;
  const int z = wb >> 12;            // 0..2
  const int rem = wb & 4095;
  const int nt = (rem & 63) * 32;
  const int k0 = (rem >> 6) * 32;
  const float* src;
  unsigned short* dst;
  int Nd, scol0, drow0;
  if (z == 0) {
    src = Wq; Nd = 2048; scol0 = nt; drow0 = nt; dst = wqkvt;
  } else if (z == 1) {
    src = Wo; Nd = 2048; scol0 = nt; drow0 = nt; dst = wot;
  } else {
    if (nt >= 1024) return;          // block-uniform
    Nd = 512; dst = wqkvt; drow0 = 2048 + nt;
    if (nt < 512) { src = Wk; scol0 = nt; }
    else          { src = Wv; scol0 = nt - 512; }
  }
  const int tx = threadIdx.x & 31, ty = threadIdx.x >> 5;
  for (int i = 0; i < 32; i += 8)
    tile[ty + i][tx] = src[(size_t)(k0 + ty + i) * Nd + scol0 + tx];
  __syncthreads();
  for (int i = 0; i < 32; i += 8)
    dst[(size_t)(drow0 + ty + i) * HIDDEN + k0 + tx] = f2bf(tile[tx][ty + i]);
}

// ------- O-proj: C[M][N] fp32 = A @ Bt^T, 32x32x16 MFMA (verified round-6) ----
__global__ __launch_bounds__(256, 3)
void gemm_bf16_kernel(const unsigned short* __restrict__ A,
                      const unsigned short* __restrict__ Bt,
                      float* __restrict__ C, int M, int N, int K) {
  __shared__ unsigned short As[128 * 64];
  __shared__ unsigned short Bs[128 * 64];
  const int tid = threadIdx.x;
  const int wave = tid >> 6, lane = tid & 63;
  const int c5 = lane & 31, h5 = lane >> 5;
  const int m0 = blockIdx.x * 128, n0 = blockIdx.y * 128;
  const int wm = (wave >> 1) * 64, wn = (wave & 1) * 64;
  const int srow8 = lane >> 3;
  const int scol = (((lane & 7) ^ srow8) * 8);

  floatx16 acc[2][2] = {};

  for (int kt = 0; kt < K; kt += 64) {
    __syncthreads();
#pragma unroll
    for (int t = 0; t < 4; ++t) {
      int row = t * 32 + wave * 8 + srow8;
      __builtin_amdgcn_global_load_lds(
          (const __attribute__((address_space(1))) unsigned int*)&A[(size_t)(m0 + row) * K + kt + scol],
          (__attribute__((address_space(3))) unsigned int*)&As[(t * 32 + wave * 8) * 64],
          16, 0, 0);
    }
#pragma unroll
    for (int t = 0; t < 4; ++t) {
      int row = t * 32 + wave * 8 + srow8;
      __builtin_amdgcn_global_load_lds(
          (const __attribute__((address_space(1))) unsigned int*)&Bt[(size_t)(n0 + row) * K + kt + scol],
          (__attribute__((address_space(3))) unsigned int*)&Bs[(t * 32 + wave * 8) * 64],
          16, 0, 0);
    }
    __syncthreads();
#pragma unroll
    for (int ks = 0; ks < 4; ++ks) {
      const int ck = ((2 * ks + h5) ^ (c5 & 7)) * 8;
      short8 a0 = *(const short8*)&As[(wm + c5) * 64 + ck];
      short8 a1 = *(const short8*)&As[(wm + 32 + c5) * 64 + ck];
      short8 b0 = *(const short8*)&Bs[(wn + c5) * 64 + ck];
      short8 b1 = *(const short8*)&Bs[(wn + 32 + c5) * 64 + ck];
      acc[0][0] = __builtin_amdgcn_mfma_f32_32x32x16_bf16(a0, b0, acc[0][0], 0, 0, 0);
      acc[0][1] = __builtin_amdgcn_mfma_f32_32x32x16_bf16(a0, b1, acc[0][1], 0, 0, 0);
      acc[1][0] = __builtin_amdgcn_mfma_f32_32x32x16_bf16(a1, b0, acc[1][0], 0, 0, 0);
      acc[1][1] = __builtin_amdgcn_mfma_f32_32x32x16_bf16(a1, b1, acc[1][1], 0, 0, 0);
    }
  }
#pragma unroll
  for (int bi = 0; bi < 2; ++bi)
#pragma unroll
    for (int bj = 0; bj < 2; ++bj) {
      const int colg = n0 + wn + bj * 32 + c5;
#pragma unroll
      for (int reg = 0; reg < 16; ++reg) {
        const int rowg = m0 + wm + bi * 32 + (reg & 3) + 4 * h5 + 8 * (reg >> 2);
        C[(size_t)rowg * N + colg] = acc[bi][bj][reg];
      }
    }
}

// ------- QKV GEMM with fused RMSNorm+RoPE (Q/K) and V-transpose epilogue -------
// (unchanged from verified round-4: qkv ~70us, conflicts 164K)
__global__ __launch_bounds__(256, 3)
void gemm_qkv_kernel(const unsigned short* __restrict__ A,    // hb [MT][2048]
                     const unsigned short* __restrict__ Bt,   // wqkvt [3072][2048]
                     const float* __restrict__ qw,
                     const float* __restrict__ kw,
                     const float* __restrict__ cosb,
                     const float* __restrict__ sinb,
                     unsigned short* __restrict__ Qb,   // [NB][NH][SEQ][HD]
                     unsigned short* __restrict__ Kbb,  // [NB][NKV][SEQ][HD]
                     unsigned short* __restrict__ Vt) { // [NB][NKV][HD][SEQ]
  __shared__ __align__(16) char sh[32768];
  unsigned short* As = (unsigned short*)sh;              // [128][64] (16 KB)
  unsigned short* Bs = (unsigned short*)(sh + 16384);    // [128][64] (16 KB)
  float* pscr = (float*)sh;                              // [4][64][20] (20 KB)
  float* pssq = (float*)(sh + 20480);                    // [2][128]   (1 KB)
  const int tid = threadIdx.x;
  const int wave = tid >> 6, lane = tid & 63;
  const int quad = lane >> 4, l16 = lane & 15;
  const int nwg = gridDim.x * gridDim.y;
  const int orig = blockIdx.y * gridDim.x + blockIdx.x;
  const int lin = (orig & 7) * (nwg >> 3) + (orig >> 3);
  const int bx = lin % gridDim.x, by = lin / gridDim.x;
  const int m0 = bx * 128, n0 = by * 128;
  const int wm = (wave >> 1) * 64, wn = (wave & 1) * 64;
  const int srow8 = lane >> 3;
  const int scol = (((lane & 7) ^ srow8) * 8);
  const int rsw = (l16 & 7);

  floatx4 acc[4][4] = {};

  for (int kt = 0; kt < HIDDEN; kt += 64) {
    __syncthreads();
#pragma unroll
    for (int t = 0; t < 4; ++t) {
      int row = t * 32 + wave * 8 + srow8;
      __builtin_amdgcn_global_load_lds(
          (const __attribute__((address_space(1))) unsigned int*)&A[(size_t)(m0 + row) * HIDDEN + kt + scol],
          (__attribute__((address_space(3))) unsigned int*)&As[(t * 32 + wave * 8) * 64],
          16, 0, 0);
    }
#pragma unroll
    for (int t = 0; t < 4; ++t) {
      int row = t * 32 + wave * 8 + srow8;
      __builtin_amdgcn_global_load_lds(
          (const __attribute__((address_space(1))) unsigned int*)&Bt[(size_t)(n0 + row) * HIDDEN + kt + scol],
          (__attribute__((address_space(3))) unsigned int*)&Bs[(t * 32 + wave * 8) * 64],
          16, 0, 0);
    }
    __syncthreads();
#pragma unroll
    for (int kk = 0; kk < 2; ++kk) {
      const int ck = ((kk * 4 + quad) ^ rsw) * 8;
      short8 af[4], bf[4];
#pragma unroll
      for (int i = 0; i < 4; i++)
        af[i] = *(const short8*)&As[(wm + i * 16 + l16) * 64 + ck];
#pragma unroll
      for (int j = 0; j < 4; j++)
        bf[j] = *(const short8*)&Bs[(wn + j * 16 + l16) * 64 + ck];
#pragma unroll
      for (int i = 0; i < 4; i++)
#pragma unroll
        for (int j = 0; j < 4; j++)
          acc[i][j] = __builtin_amdgcn_mfma_f32_16x16x32_bf16(af[i], bf[j], acc[i][j], 0, 0, 0);
    }
  }

  const int head = n0 >> 7;
  if (head >= NH + NKV) {
    const int kv = head - (NH + NKV);
#pragma unroll
    for (int i = 0; i < 4; ++i) {
      int m = m0 + wm + i * 16 + quad * 4;
      int b = m >> 11, sbase = m & (SEQ - 1);
#pragma unroll
      for (int j = 0; j < 4; ++j) {
        int d = wn + j * 16 + l16;
        ushort4 pk;
        pk.x = f2bf(acc[i][j][0]); pk.y = f2bf(acc[i][j][1]);
        pk.z = f2bf(acc[i][j][2]); pk.w = f2bf(acc[i][j][3]);
        *(ushort4*)&Vt[((size_t)(b * NKV + kv) * HD + d) * SEQ + sbase] = pk;
      }
    }
    return;  // head is block-uniform: no barrier divergence
  }

  __syncthreads();  // all waves done reading As/Bs before pscr/pssq reuse the LDS
  const float* w = (head < NH) ? qw : kw;
  float wown[4], wpar[4];
#pragma unroll
  for (int j = 0; j < 4; ++j) {
    wown[j] = w[wn + j * 16 + l16];
    wpar[j] = w[(wn ^ 64) + j * 16 + l16];
  }
#pragma unroll
  for (int i = 0; i < 4; ++i) {
    float sq[4];
#pragma unroll
    for (int r = 0; r < 4; ++r) {
      float s2 = acc[i][0][r] * acc[i][0][r] + acc[i][1][r] * acc[i][1][r] +
                 acc[i][2][r] * acc[i][2][r] + acc[i][3][r] * acc[i][3][r];
#pragma unroll
      for (int off = 1; off < 16; off <<= 1) s2 += __shfl_xor(s2, off, 64);
      sq[r] = s2;
    }
    if (l16 == 0)
      *(float4*)&pssq[(wn >> 6) * 128 + wm + i * 16 + quad * 4] = make_float4(sq[0], sq[1], sq[2], sq[3]);
#pragma unroll
    for (int j = 0; j < 4; ++j)
      *(float4*)&pscr[(wave * 64 + j * 16 + l16) * 20 + quad * 4] = *(float4*)&acc[i][j];
    __syncthreads();
    float4 oss = *(const float4*)&pssq[((wn >> 6) ^ 1) * 128 + wm + i * 16 + quad * 4];
    float rr[4];
    rr[0] = rsqrtf((sq[0] + oss.x) * (1.0f / 128.0f) + 1e-6f);
    rr[1] = rsqrtf((sq[1] + oss.y) * (1.0f / 128.0f) + 1e-6f);
    rr[2] = rsqrtf((sq[2] + oss.z) * (1.0f / 128.0f) + 1e-6f);
    rr[3] = rsqrtf((sq[3] + oss.w) * (1.0f / 128.0f) + 1e-6f);
    int mbase = m0 + wm + i * 16 + quad * 4;
    int b = mbase >> 11, sbase = mbase & (SEQ - 1);
#pragma unroll
    for (int j = 0; j < 4; ++j) {
      float4 par = *(const float4*)&pscr[((wave ^ 1) * 64 + j * 16 + l16) * 20 + quad * 4];
      float pr[4] = {par.x, par.y, par.z, par.w};
      int d = wn + j * 16 + l16;
      unsigned short* dst = (head < NH)
          ? Qb + ((size_t)(b * NH + head) * SEQ + sbase) * HD + d
          : Kbb + ((size_t)(b * NKV + (head - NH)) * SEQ + sbase) * HD + d;
#pragma unroll
      for (int r = 0; r < 4; ++r) {
        int s = sbase + r;
        float c = cosb[s * HD + d], sn = sinb[s * HD + d];
        float xo = acc[i][j][r] * rr[r] * wown[j];
        float xp = pr[r] * rr[r] * wpar[j];
        float out = (wn == 0) ? (xo * c - xp * sn) : (xo * c + xp * sn);
        dst[(size_t)r * HD] = f2bf(out);
      }
    }
    __syncthreads();  // pscr/pssq reused next i
  }
}

// ------- flash attention: round-6 verified structure (seg-paired uniform
// blocks, 64-row Q-tile, syncthreads pair) + T5 setprio on MFMA clusters +
// exp2-based softmax (2 VALU/elem instead of 4 on the measured-dominant pipe).
__device__ __forceinline__ void stage_rows(const unsigned short* gbase, int rowstride,
                                           unsigned short* lds, int wave, int quad,
                                           int s_cx, int s_hb) {
#pragma unroll
  for (int i = 0; i < 8; ++i) {
    const int row = i * 16 + wave * 4 + quad;                     // row&3 == quad
    const int sck = s_cx ^ (((2 * i + s_hb) & 3) << 2);           // chunk ^ f(row)
    __builtin_amdgcn_global_load_lds(
        (const __attribute__((address_space(1))) unsigned int*)(gbase + (size_t)row * rowstride + sck * 8),
        (__attribute__((address_space(3))) unsigned int*)(lds + (i * 4 + wave) * 512),
        16, 0, 0);
  }
}

__global__ __launch_bounds__(256, 2)
void attn_kernel(const unsigned short* __restrict__ Q,   // [NB][NH][SEQ][HD]
                 const unsigned short* __restrict__ Kb,  // [NB][NKV][SEQ][HD]
                 const unsigned short* __restrict__ Vt,  // [NB][NKV][HD][SEQ]
                 unsigned short* __restrict__ O) {       // [MT][NH*HD]
  __shared__ __align__(16) unsigned short KVs[2][128 * 128];  // 2 x 32 KiB
  const int tid = threadIdx.x;
  const int wave = tid >> 6, lane = tid & 63;
  const int quad = lane >> 4, l16 = lane & 15;
  const int l3 = l16 & 3, s3 = l16 >> 3, s2 = (l16 >> 2) & 1;
  const int bh = blockIdx.x & 31;
  const int pr = blockIdx.x >> 5;                       // 0..15 -> pair (31-pr, pr)
  const int b = bh >> 4, h = bh & 15, kvh = h >> 2;

  const int s_cx = (lane & 15) ^ quad;                  // staging chunk ^ (row&3)
  const int s_hb = wave >> 1;                           // (4*wave+quad)>>3
  const int krbase = 16 * s3 + 8 * s2 + l3;             // permuted K-row base
  const int f_k = l3 | ((2 * s3 + s2) << 2);            // f(krow), j-independent
  const int kvqb = 16 * (quad >> 1) + 8 * (quad & 1);   // kv label base per quad
  const int qsw = (lane & 48) | (quad << 2);            // col->row state shfl base
  const float C2 = 0.08838834764831845f * 1.44269504088896f;  // CS * log2(e)

  const unsigned short* Kg0 = Kb + (size_t)((b * NKV + kvh) * SEQ) * HD;
  const unsigned short* Vg0 = Vt + (size_t)((b * NKV + kvh) * HD) * SEQ;

  int p = 0;
#pragma unroll 1
  for (int seg = 0; seg < 2; ++seg) {
    const int qt = seg ? pr : (31 - pr);
    const int q0 = qt * 64;
    const int nkt = (qt >> 1) + 1;
    const int qglob = q0 + wave * 16 + l16;             // lane's q row

    const unsigned short* Qg = Q + (size_t)((b * NH + h) * SEQ + q0) * HD;
    short8 qf[4];
#pragma unroll
    for (int ks = 0; ks < 4; ++ks)
      qf[ks] = *(const short8*)&Qg[(size_t)(wave * 16 + l16) * HD + ks * 32 + quad * 8];

    floatx4 oacc[8] = {};
    float mrow = -1e30f, lrow = 0.f;

    stage_rows(Kg0, 128, KVs[p], wave, quad, s_cx, s_hb);        // K tile 0
    __syncthreads();

    for (int kt = 0; kt < nkt; ++kt) {
      const unsigned short* KVp = KVs[p];
      // ---- S^T = K @ Q^T : rows=kv (permuted labels), cols=q ----
      floatx4 sc[8] = {};
      __builtin_amdgcn_s_setprio(1);
#pragma unroll
      for (int ks = 0; ks < 4; ++ks) {
        const int cko = ((ks * 4 + quad) ^ f_k) * 8;
#pragma unroll
        for (int j = 0; j < 8; ++j) {
          const short8 kf = *(const short8*)&KVp[(krbase + 32 * (j >> 1) + 4 * (j & 1)) * 128 + cko];
          sc[j] = __builtin_amdgcn_mfma_f32_16x16x32_bf16(kf, qf[ks], sc[j], 0, 0, 0);
        }
      }
      __builtin_amdgcn_s_setprio(0);
      __syncthreads();  // all K reads done; prev PV reads done
      // V_kt overwrites current buffer; prefetch K_{kt+1} into the other one.
      stage_rows(Vg0 + kt * 128, SEQ, KVs[p], wave, quad, s_cx, s_hb);
      if (kt + 1 < nkt)
        stage_rows(Kg0 + (size_t)(kt + 1) * 128 * HD, 128, KVs[p ^ 1], wave, quad, s_cx, s_hb);

      // ---- causal mask (last tile only; kv via relabel formula) ----
      if (kt == nkt - 1) {
#pragma unroll
        for (int j = 0; j < 8; ++j) {
          const int kvj = kt * 128 + 32 * (j >> 1) + 4 * (j & 1) + kvqb;
#pragma unroll
          for (int r = 0; r < 4; ++r)
            if (kvj + r > qglob) sc[j][r] = -1e30f;
        }
      }
      // ---- online softmax: in-lane over 32 kv, cross-quad via 2 shfl_xor ----
      float mx = -1e30f;
#pragma unroll
      for (int j = 0; j < 8; ++j)
        mx = fmaxf(mx, fmaxf(fmaxf(sc[j][0], sc[j][1]), fmaxf(sc[j][2], sc[j][3])));
      mx = fmaxf(mx, __shfl_xor(mx, 16, 64));
      mx = fmaxf(mx, __shfl_xor(mx, 32, 64));
      if (!__all(mx <= mrow + 62.0f)) {   // defer-max: skip rescale when growth small
        const float mnew = fmaxf(mrow, mx);
        const float al = exp2f((mrow - mnew) * C2);
        mrow = mnew;
        lrow *= al;
#pragma unroll
        for (int r = 0; r < 4; ++r) {
          const float ar = __shfl(al, qsw + r, 64);     // col-state -> row-space
#pragma unroll
          for (int t = 0; t < 8; ++t) oacc[t][r] *= ar;
        }
      }
      const float mc2 = mrow * C2;
      float rs = 0.f;
#pragma unroll
      for (int j = 0; j < 8; ++j)
#pragma unroll
        for (int r = 0; r < 4; ++r) {
          const float pe = exp2f(sc[j][r] * C2 - mc2);  // fma + v_exp
          sc[j][r] = pe;
          rs += pe;
        }
      rs += __shfl_xor(rs, 16, 64);
      rs += __shfl_xor(rs, 32, 64);
      lrow += rs;

      // ---- pack P to bf16; lane-local by construction ----
      unsigned int pk[8][2];
#pragma unroll
      for (int j = 0; j < 8; ++j) {
        pk[j][0] = cvt_pk_bf16(sc[j][0], sc[j][1]);
        pk[j][1] = cvt_pk_bf16(sc[j][2], sc[j][3]);
      }
      __syncthreads();  // V ready (drains staging loads)
      // ---- O += P @ V ----
      __builtin_amdgcn_s_setprio(1);
#pragma unroll
      for (int ks = 0; ks < 4; ++ks) {
        union { unsigned int u[4]; short8 s; } au;
        au.u[0] = pk[2 * ks][0];     au.u[1] = pk[2 * ks][1];
        au.u[2] = pk[2 * ks + 1][0]; au.u[3] = pk[2 * ks + 1][1];
#pragma unroll
        for (int t = 0; t < 8; ++t) {
          const int fv = l3 | (((2 * t + s3) & 3) << 2);
          const short8 vf = *(const short8*)&KVp[(t * 16 + l16) * 128 + (((ks * 4 + quad) ^ fv) * 8)];
          oacc[t] = __builtin_amdgcn_mfma_f32_16x16x32_bf16(au.s, vf, oacc[t], 0, 0, 0);
        }
      }
      __builtin_amdgcn_s_setprio(0);
      p ^= 1;
    }
    // ---- epilogue: fetch 1/l per output row, store ----
    float li[4];
#pragma unroll
    for (int r = 0; r < 4; ++r) li[r] = 1.0f / __shfl(lrow, qsw + r, 64);
#pragma unroll
    for (int t = 0; t < 8; ++t) {
      const int col = h * HD + t * 16 + l16;
#pragma unroll
      for (int r = 0; r < 4; ++r) {
        const int row = q0 + wave * 16 + quad * 4 + r;
        O[(size_t)(b * SEQ + row) * (NH * HD) + col] = f2bf(oacc[t][r] * li[r]);
      }
    }
  }
}

extern "C" void kernel_launch(void* const* d_in, const int* in_sizes, int n_in,
                              void* d_out, int out_size, void* d_ws, size_t ws_size,
                              hipStream_t stream) {
  const float* hidden = (const float*)d_in[0];
  const float* cosb   = (const float*)d_in[1];
  const float* sinb   = (const float*)d_in[2];
  const float* Wq     = (const float*)d_in[3];
  const float* Wk     = (const float*)d_in[4];
  const float* Wv     = (const float*)d_in[5];
  const float* Wo     = (const float*)d_in[6];
  const float* qw     = (const float*)d_in[7];
  const float* kw     = (const float*)d_in[8];
  (void)in_sizes; (void)n_in; (void)out_size; (void)ws_size;

  char* ws = (char*)d_ws;
  size_t off = 0;
  auto alloc = [&](size_t n) { char* p = ws + off; off += (n + 255) & ~(size_t)255; return p; };

  unsigned short* hb    = (unsigned short*)alloc((size_t)MT * HIDDEN * 2);   // (16 MB)
  unsigned short* wqkvt = (unsigned short*)alloc((size_t)NQKV * HIDDEN * 2); // (12 MB)
  unsigned short* wot   = (unsigned short*)alloc((size_t)2048 * 2048 * 2);   // (8 MB)
  unsigned short* Qb  = (unsigned short*)alloc((size_t)MT * 2048 * 2);  // (16 MB)
  unsigned short* Kbb = (unsigned short*)alloc((size_t)MT * 512 * 2);   // (4 MB)
  unsigned short* Vtb = (unsigned short*)alloc((size_t)MT * 512 * 2);   // (4 MB)
  unsigned short* Ob  = (unsigned short*)alloc((size_t)MT * 2048 * 2);  // (16 MB)

  // fused prep: cast (8192 blocks) + weight transpose (12288 blocks)
  prep_kernel<<<20480, 256, 0, stream>>>(hidden, hb, Wq, Wk, Wv, Wo, wqkvt, wot);

  // fused QKV projection + norm/rope/V-transpose epilogue: grid 32x24 = 768 blocks
  gemm_qkv_kernel<<<dim3(MT / 128, NQKV / 128), 256, 0, stream>>>(
      hb, wqkvt, qw, kw, cosb, sinb, Qb, Kbb, Vtb);

  // paired q-tiles: 16 pairs x 32 (b,h) = 512 blocks, uniform 17 kv-tiles each
  attn_kernel<<<512, 256, 0, stream>>>(Qb, Kbb, Vtb, Ob);

  // O-projection: 32x32x16 MFMA
  gemm_bf16_kernel<<<dim3(MT / 128, 16), 256, 0, stream>>>(Ob, wot, (float*)d_out, MT, 2048, 2048);
}

// Round 9
// 288.311 us; speedup vs baseline: 1.0183x; 1.0103x over previous
//
#include <hip/hip_runtime.h>

typedef float floatx4 __attribute__((ext_vector_type(4)));
typedef float floatx16 __attribute__((ext_vector_type(16)));
typedef short short8 __attribute__((ext_vector_type(8)));

#define HIDDEN 2048
#define NH 16
#define NKV 4
#define HD 128
#define NB 2
#define SEQ 2048
#define MT (NB * SEQ)  // 4096
#define NQKV 3072      // fused projection width: 2048 Q + 512 K + 512 V

// native exp2 = single v_exp_f32 (what __expf is built from, minus the mul).
// exp2f() lowers to precise __ocml_exp2_f32 (~10 VALU) -- round-8's regression.
extern "C" __device__ float __ocml_native_exp2_f32(float);
#define FEXP2(x) __ocml_native_exp2_f32(x)

__device__ __forceinline__ unsigned short f2bf(float x) {
  union { float f; unsigned u; } v; v.f = x;
  unsigned r = v.u + 0x7FFFu + ((v.u >> 16) & 1u);  // RNE
  return (unsigned short)(r >> 16);
}

__device__ __forceinline__ unsigned int cvt_pk_bf16(float lo, float hi) {
  unsigned int r;
  asm("v_cvt_pk_bf16_f32 %0, %1, %2" : "=v"(r) : "v"(lo), "v"(hi));
  return r;
}

// ------- fused prep: contiguous fp32->bf16 cast + weight transpose/cast -------
__global__ void prep_kernel(const float* __restrict__ hidden,
                            unsigned short* __restrict__ hb,
                            const float* __restrict__ Wq,
                            const float* __restrict__ Wk,
                            const float* __restrict__ Wv,
                            const float* __restrict__ Wo,
                            unsigned short* __restrict__ wqkvt,
                            unsigned short* __restrict__ wot) {
  const int bid = blockIdx.x;
  if (bid < 8192) {
    int i = bid * 256 + threadIdx.x;
    float4 v = ((const float4*)hidden)[i];
    ushort4 o;
    o.x = f2bf(v.x); o.y = f2bf(v.y); o.z = f2bf(v.z); o.w = f2bf(v.w);
    ((ushort4*)hb)[i] = o;
    return;
  }
  __shared__ float tile[32][33];
  const int wb = bid - 8192;
  const int z = wb >> 12;            // 0..2
  const int rem = wb & 4095;
  const int nt = (rem & 63) * 32;
  const int k0 = (rem >> 6) * 32;
  const float* src;
  unsigned short* dst;
  int Nd, scol0, drow0;
  if (z == 0) {
    src = Wq; Nd = 2048; scol0 = nt; drow0 = nt; dst = wqkvt;
  } else if (z == 1) {
    src = Wo; Nd = 2048; scol0 = nt; drow0 = nt; dst = wot;
  } else {
    if (nt >= 1024) return;          // block-uniform
    Nd = 512; dst = wqkvt; drow0 = 2048 + nt;
    if (nt < 512) { src = Wk; scol0 = nt; }
    else          { src = Wv; scol0 = nt - 512; }
  }
  const int tx = threadIdx.x & 31, ty = threadIdx.x >> 5;
  for (int i = 0; i < 32; i += 8)
    tile[ty + i][tx] = src[(size_t)(k0 + ty + i) * Nd + scol0 + tx];
  __syncthreads();
  for (int i = 0; i < 32; i += 8)
    dst[(size_t)(drow0 + ty + i) * HIDDEN + k0 + tx] = f2bf(tile[tx][ty + i]);
}

// ------- O-proj: C[M][N] fp32 = A @ Bt^T, 32x32x16 MFMA (verified round-6) ----
__global__ __launch_bounds__(256, 3)
void gemm_bf16_kernel(const unsigned short* __restrict__ A,
                      const unsigned short* __restrict__ Bt,
                      float* __restrict__ C, int M, int N, int K) {
  __shared__ unsigned short As[128 * 64];
  __shared__ unsigned short Bs[128 * 64];
  const int tid = threadIdx.x;
  const int wave = tid >> 6, lane = tid & 63;
  const int c5 = lane & 31, h5 = lane >> 5;
  const int m0 = blockIdx.x * 128, n0 = blockIdx.y * 128;
  const int wm = (wave >> 1) * 64, wn = (wave & 1) * 64;
  const int srow8 = lane >> 3;
  const int scol = (((lane & 7) ^ srow8) * 8);

  floatx16 acc[2][2] = {};

  for (int kt = 0; kt < K; kt += 64) {
    __syncthreads();
#pragma unroll
    for (int t = 0; t < 4; ++t) {
      int row = t * 32 + wave * 8 + srow8;
      __builtin_amdgcn_global_load_lds(
          (const __attribute__((address_space(1))) unsigned int*)&A[(size_t)(m0 + row) * K + kt + scol],
          (__attribute__((address_space(3))) unsigned int*)&As[(t * 32 + wave * 8) * 64],
          16, 0, 0);
    }
#pragma unroll
    for (int t = 0; t < 4; ++t) {
      int row = t * 32 + wave * 8 + srow8;
      __builtin_amdgcn_global_load_lds(
          (const __attribute__((address_space(1))) unsigned int*)&Bt[(size_t)(n0 + row) * K + kt + scol],
          (__attribute__((address_space(3))) unsigned int*)&Bs[(t * 32 + wave * 8) * 64],
          16, 0, 0);
    }
    __syncthreads();
#pragma unroll
    for (int ks = 0; ks < 4; ++ks) {
      const int ck = ((2 * ks + h5) ^ (c5 & 7)) * 8;
      short8 a0 = *(const short8*)&As[(wm + c5) * 64 + ck];
      short8 a1 = *(const short8*)&As[(wm + 32 + c5) * 64 + ck];
      short8 b0 = *(const short8*)&Bs[(wn + c5) * 64 + ck];
      short8 b1 = *(const short8*)&Bs[(wn + 32 + c5) * 64 + ck];
      acc[0][0] = __builtin_amdgcn_mfma_f32_32x32x16_bf16(a0, b0, acc[0][0], 0, 0, 0);
      acc[0][1] = __builtin_amdgcn_mfma_f32_32x32x16_bf16(a0, b1, acc[0][1], 0, 0, 0);
      acc[1][0] = __builtin_amdgcn_mfma_f32_32x32x16_bf16(a1, b0, acc[1][0], 0, 0, 0);
      acc[1][1] = __builtin_amdgcn_mfma_f32_32x32x16_bf16(a1, b1, acc[1][1], 0, 0, 0);
    }
  }
#pragma unroll
  for (int bi = 0; bi < 2; ++bi)
#pragma unroll
    for (int bj = 0; bj < 2; ++bj) {
      const int colg = n0 + wn + bj * 32 + c5;
#pragma unroll
      for (int reg = 0; reg < 16; ++reg) {
        const int rowg = m0 + wm + bi * 32 + (reg & 3) + 4 * h5 + 8 * (reg >> 2);
        C[(size_t)rowg * N + colg] = acc[bi][bj][reg];
      }
    }
}

// ------- QKV GEMM with fused RMSNorm+RoPE (Q/K) and V-transpose epilogue -------
// (unchanged from verified round-4: qkv ~70us, conflicts 164K)
__global__ __launch_bounds__(256, 3)
void gemm_qkv_kernel(const unsigned short* __restrict__ A,    // hb [MT][2048]
                     const unsigned short* __restrict__ Bt,   // wqkvt [3072][2048]
                     const float* __restrict__ qw,
                     const float* __restrict__ kw,
                     const float* __restrict__ cosb,
                     const float* __restrict__ sinb,
                     unsigned short* __restrict__ Qb,   // [NB][NH][SEQ][HD]
                     unsigned short* __restrict__ Kbb,  // [NB][NKV][SEQ][HD]
                     unsigned short* __restrict__ Vt) { // [NB][NKV][HD][SEQ]
  __shared__ __align__(16) char sh[32768];
  unsigned short* As = (unsigned short*)sh;              // [128][64] (16 KB)
  unsigned short* Bs = (unsigned short*)(sh + 16384);    // [128][64] (16 KB)
  float* pscr = (float*)sh;                              // [4][64][20] (20 KB)
  float* pssq = (float*)(sh + 20480);                    // [2][128]   (1 KB)
  const int tid = threadIdx.x;
  const int wave = tid >> 6, lane = tid & 63;
  const int quad = lane >> 4, l16 = lane & 15;
  const int nwg = gridDim.x * gridDim.y;
  const int orig = blockIdx.y * gridDim.x + blockIdx.x;
  const int lin = (orig & 7) * (nwg >> 3) + (orig >> 3);
  const int bx = lin % gridDim.x, by = lin / gridDim.x;
  const int m0 = bx * 128, n0 = by * 128;
  const int wm = (wave >> 1) * 64, wn = (wave & 1) * 64;
  const int srow8 = lane >> 3;
  const int scol = (((lane & 7) ^ srow8) * 8);
  const int rsw = (l16 & 7);

  floatx4 acc[4][4] = {};

  for (int kt = 0; kt < HIDDEN; kt += 64) {
    __syncthreads();
#pragma unroll
    for (int t = 0; t < 4; ++t) {
      int row = t * 32 + wave * 8 + srow8;
      __builtin_amdgcn_global_load_lds(
          (const __attribute__((address_space(1))) unsigned int*)&A[(size_t)(m0 + row) * HIDDEN + kt + scol],
          (__attribute__((address_space(3))) unsigned int*)&As[(t * 32 + wave * 8) * 64],
          16, 0, 0);
    }
#pragma unroll
    for (int t = 0; t < 4; ++t) {
      int row = t * 32 + wave * 8 + srow8;
      __builtin_amdgcn_global_load_lds(
          (const __attribute__((address_space(1))) unsigned int*)&Bt[(size_t)(n0 + row) * HIDDEN + kt + scol],
          (__attribute__((address_space(3))) unsigned int*)&Bs[(t * 32 + wave * 8) * 64],
          16, 0, 0);
    }
    __syncthreads();
#pragma unroll
    for (int kk = 0; kk < 2; ++kk) {
      const int ck = ((kk * 4 + quad) ^ rsw) * 8;
      short8 af[4], bf[4];
#pragma unroll
      for (int i = 0; i < 4; i++)
        af[i] = *(const short8*)&As[(wm + i * 16 + l16) * 64 + ck];
#pragma unroll
      for (int j = 0; j < 4; j++)
        bf[j] = *(const short8*)&Bs[(wn + j * 16 + l16) * 64 + ck];
#pragma unroll
      for (int i = 0; i < 4; i++)
#pragma unroll
        for (int j = 0; j < 4; j++)
          acc[i][j] = __builtin_amdgcn_mfma_f32_16x16x32_bf16(af[i], bf[j], acc[i][j], 0, 0, 0);
    }
  }

  const int head = n0 >> 7;
  if (head >= NH + NKV) {
    const int kv = head - (NH + NKV);
#pragma unroll
    for (int i = 0; i < 4; ++i) {
      int m = m0 + wm + i * 16 + quad * 4;
      int b = m >> 11, sbase = m & (SEQ - 1);
#pragma unroll
      for (int j = 0; j < 4; ++j) {
        int d = wn + j * 16 + l16;
        ushort4 pk;
        pk.x = f2bf(acc[i][j][0]); pk.y = f2bf(acc[i][j][1]);
        pk.z = f2bf(acc[i][j][2]); pk.w = f2bf(acc[i][j][3]);
        *(ushort4*)&Vt[((size_t)(b * NKV + kv) * HD + d) * SEQ + sbase] = pk;
      }
    }
    return;  // head is block-uniform: no barrier divergence
  }

  __syncthreads();  // all waves done reading As/Bs before pscr/pssq reuse the LDS
  const float* w = (head < NH) ? qw : kw;
  float wown[4], wpar[4];
#pragma unroll
  for (int j = 0; j < 4; ++j) {
    wown[j] = w[wn + j * 16 + l16];
    wpar[j] = w[(wn ^ 64) + j * 16 + l16];
  }
#pragma unroll
  for (int i = 0; i < 4; ++i) {
    float sq[4];
#pragma unroll
    for (int r = 0; r < 4; ++r) {
      float s2 = acc[i][0][r] * acc[i][0][r] + acc[i][1][r] * acc[i][1][r] +
                 acc[i][2][r] * acc[i][2][r] + acc[i][3][r] * acc[i][3][r];
#pragma unroll
      for (int off = 1; off < 16; off <<= 1) s2 += __shfl_xor(s2, off, 64);
      sq[r] = s2;
    }
    if (l16 == 0)
      *(float4*)&pssq[(wn >> 6) * 128 + wm + i * 16 + quad * 4] = make_float4(sq[0], sq[1], sq[2], sq[3]);
#pragma unroll
    for (int j = 0; j < 4; ++j)
      *(float4*)&pscr[(wave * 64 + j * 16 + l16) * 20 + quad * 4] = *(float4*)&acc[i][j];
    __syncthreads();
    float4 oss = *(const float4*)&pssq[((wn >> 6) ^ 1) * 128 + wm + i * 16 + quad * 4];
    float rr[4];
    rr[0] = rsqrtf((sq[0] + oss.x) * (1.0f / 128.0f) + 1e-6f);
    rr[1] = rsqrtf((sq[1] + oss.y) * (1.0f / 128.0f) + 1e-6f);
    rr[2] = rsqrtf((sq[2] + oss.z) * (1.0f / 128.0f) + 1e-6f);
    rr[3] = rsqrtf((sq[3] + oss.w) * (1.0f / 128.0f) + 1e-6f);
    int mbase = m0 + wm + i * 16 + quad * 4;
    int b = mbase >> 11, sbase = mbase & (SEQ - 1);
#pragma unroll
    for (int j = 0; j < 4; ++j) {
      float4 par = *(const float4*)&pscr[((wave ^ 1) * 64 + j * 16 + l16) * 20 + quad * 4];
      float pr[4] = {par.x, par.y, par.z, par.w};
      int d = wn + j * 16 + l16;
      unsigned short* dst = (head < NH)
          ? Qb + ((size_t)(b * NH + head) * SEQ + sbase) * HD + d
          : Kbb + ((size_t)(b * NKV + (head - NH)) * SEQ + sbase) * HD + d;
#pragma unroll
      for (int r = 0; r < 4; ++r) {
        int s = sbase + r;
        float c = cosb[s * HD + d], sn = sinb[s * HD + d];
        float xo = acc[i][j][r] * rr[r] * wown[j];
        float xp = pr[r] * rr[r] * wpar[j];
        float out = (wn == 0) ? (xo * c - xp * sn) : (xo * c + xp * sn);
        dst[(size_t)r * HD] = f2bf(out);
      }
    }
    __syncthreads();  // pscr/pssq reused next i
  }
}

// ------- flash attention: round-6 verified structure + setprio + NATIVE exp2
// softmax (fma + v_exp_f32 = 2 ops/elem on the measured-dominant VALU pipe).
__device__ __forceinline__ void stage_rows(const unsigned short* gbase, int rowstride,
                                           unsigned short* lds, int wave, int quad,
                                           int s_cx, int s_hb) {
#pragma unroll
  for (int i = 0; i < 8; ++i) {
    const int row = i * 16 + wave * 4 + quad;                     // row&3 == quad
    const int sck = s_cx ^ (((2 * i + s_hb) & 3) << 2);           // chunk ^ f(row)
    __builtin_amdgcn_global_load_lds(
        (const __attribute__((address_space(1))) unsigned int*)(gbase + (size_t)row * rowstride + sck * 8),
        (__attribute__((address_space(3))) unsigned int*)(lds + (i * 4 + wave) * 512),
        16, 0, 0);
  }
}

__global__ __launch_bounds__(256, 2)
void attn_kernel(const unsigned short* __restrict__ Q,   // [NB][NH][SEQ][HD]
                 const unsigned short* __restrict__ Kb,  // [NB][NKV][SEQ][HD]
                 const unsigned short* __restrict__ Vt,  // [NB][NKV][HD][SEQ]
                 unsigned short* __restrict__ O) {       // [MT][NH*HD]
  __shared__ __align__(16) unsigned short KVs[2][128 * 128];  // 2 x 32 KiB
  const int tid = threadIdx.x;
  const int wave = tid >> 6, lane = tid & 63;
  const int quad = lane >> 4, l16 = lane & 15;
  const int l3 = l16 & 3, s3 = l16 >> 3, s2 = (l16 >> 2) & 1;
  const int bh = blockIdx.x & 31;
  const int pr = blockIdx.x >> 5;                       // 0..15 -> pair (31-pr, pr)
  const int b = bh >> 4, h = bh & 15, kvh = h >> 2;

  const int s_cx = (lane & 15) ^ quad;                  // staging chunk ^ (row&3)
  const int s_hb = wave >> 1;                           // (4*wave+quad)>>3
  const int krbase = 16 * s3 + 8 * s2 + l3;             // permuted K-row base
  const int f_k = l3 | ((2 * s3 + s2) << 2);            // f(krow), j-independent
  const int kvqb = 16 * (quad >> 1) + 8 * (quad & 1);   // kv label base per quad
  const int qsw = (lane & 48) | (quad << 2);            // col->row state shfl base
  const float C2 = 0.08838834764831845f * 1.44269504088896f;  // CS * log2(e)

  const unsigned short* Kg0 = Kb + (size_t)((b * NKV + kvh) * SEQ) * HD;
  const unsigned short* Vg0 = Vt + (size_t)((b * NKV + kvh) * HD) * SEQ;

  int p = 0;
#pragma unroll 1
  for (int seg = 0; seg < 2; ++seg) {
    const int qt = seg ? pr : (31 - pr);
    const int q0 = qt * 64;
    const int nkt = (qt >> 1) + 1;
    const int qglob = q0 + wave * 16 + l16;             // lane's q row

    const unsigned short* Qg = Q + (size_t)((b * NH + h) * SEQ + q0) * HD;
    short8 qf[4];
#pragma unroll
    for (int ks = 0; ks < 4; ++ks)
      qf[ks] = *(const short8*)&Qg[(size_t)(wave * 16 + l16) * HD + ks * 32 + quad * 8];

    floatx4 oacc[8] = {};
    float mrow = -1e30f, lrow = 0.f;

    stage_rows(Kg0, 128, KVs[p], wave, quad, s_cx, s_hb);        // K tile 0
    __syncthreads();

    for (int kt = 0; kt < nkt; ++kt) {
      const unsigned short* KVp = KVs[p];
      // ---- S^T = K @ Q^T : rows=kv (permuted labels), cols=q ----
      floatx4 sc[8] = {};
      __builtin_amdgcn_s_setprio(1);
#pragma unroll
      for (int ks = 0; ks < 4; ++ks) {
        const int cko = ((ks * 4 + quad) ^ f_k) * 8;
#pragma unroll
        for (int j = 0; j < 8; ++j) {
          const short8 kf = *(const short8*)&KVp[(krbase + 32 * (j >> 1) + 4 * (j & 1)) * 128 + cko];
          sc[j] = __builtin_amdgcn_mfma_f32_16x16x32_bf16(kf, qf[ks], sc[j], 0, 0, 0);
        }
      }
      __builtin_amdgcn_s_setprio(0);
      __syncthreads();  // all K reads done; prev PV reads done
      // V_kt overwrites current buffer; prefetch K_{kt+1} into the other one.
      stage_rows(Vg0 + kt * 128, SEQ, KVs[p], wave, quad, s_cx, s_hb);
      if (kt + 1 < nkt)
        stage_rows(Kg0 + (size_t)(kt + 1) * 128 * HD, 128, KVs[p ^ 1], wave, quad, s_cx, s_hb);

      // ---- causal mask (last tile only; kv via relabel formula) ----
      if (kt == nkt - 1) {
#pragma unroll
        for (int j = 0; j < 8; ++j) {
          const int kvj = kt * 128 + 32 * (j >> 1) + 4 * (j & 1) + kvqb;
#pragma unroll
          for (int r = 0; r < 4; ++r)
            if (kvj + r > qglob) sc[j][r] = -1e30f;
        }
      }
      // ---- online softmax: in-lane over 32 kv, cross-quad via 2 shfl_xor ----
      float mx = -1e30f;
#pragma unroll
      for (int j = 0; j < 8; ++j)
        mx = fmaxf(mx, fmaxf(fmaxf(sc[j][0], sc[j][1]), fmaxf(sc[j][2], sc[j][3])));
      mx = fmaxf(mx, __shfl_xor(mx, 16, 64));
      mx = fmaxf(mx, __shfl_xor(mx, 32, 64));
      if (!__all(mx <= mrow + 62.0f)) {   // defer-max: skip rescale when growth small
        const float mnew = fmaxf(mrow, mx);
        const float al = FEXP2((mrow - mnew) * C2);
        mrow = mnew;
        lrow *= al;
#pragma unroll
        for (int r = 0; r < 4; ++r) {
          const float ar = __shfl(al, qsw + r, 64);     // col-state -> row-space
#pragma unroll
          for (int t = 0; t < 8; ++t) oacc[t][r] *= ar;
        }
      }
      const float mc2 = mrow * C2;
      float rs = 0.f;
#pragma unroll
      for (int j = 0; j < 8; ++j)
#pragma unroll
        for (int r = 0; r < 4; ++r) {
          const float pe = FEXP2(__builtin_fmaf(sc[j][r], C2, -mc2));  // fma + v_exp
          sc[j][r] = pe;
          rs += pe;
        }
      rs += __shfl_xor(rs, 16, 64);
      rs += __shfl_xor(rs, 32, 64);
      lrow += rs;

      // ---- pack P to bf16; lane-local by construction ----
      unsigned int pk[8][2];
#pragma unroll
      for (int j = 0; j < 8; ++j) {
        pk[j][0] = cvt_pk_bf16(sc[j][0], sc[j][1]);
        pk[j][1] = cvt_pk_bf16(sc[j][2], sc[j][3]);
      }
      __syncthreads();  // V ready (drains staging loads)
      // ---- O += P @ V ----
      __builtin_amdgcn_s_setprio(1);
#pragma unroll
      for (int ks = 0; ks < 4; ++ks) {
        union { unsigned int u[4]; short8 s; } au;
        au.u[0] = pk[2 * ks][0];     au.u[1] = pk[2 * ks][1];
        au.u[2] = pk[2 * ks + 1][0]; au.u[3] = pk[2 * ks + 1][1];
#pragma unroll
        for (int t = 0; t < 8; ++t) {
          const int fv = l3 | (((2 * t + s3) & 3) << 2);
          const short8 vf = *(const short8*)&KVp[(t * 16 + l16) * 128 + (((ks * 4 + quad) ^ fv) * 8)];
          oacc[t] = __builtin_amdgcn_mfma_f32_16x16x32_bf16(au.s, vf, oacc[t], 0, 0, 0);
        }
      }
      __builtin_amdgcn_s_setprio(0);
      p ^= 1;
    }
    // ---- epilogue: fetch 1/l per output row, store ----
    float li[4];
#pragma unroll
    for (int r = 0; r < 4; ++r) li[r] = 1.0f / __shfl(lrow, qsw + r, 64);
#pragma unroll
    for (int t = 0; t < 8; ++t) {
      const int col = h * HD + t * 16 + l16;
#pragma unroll
      for (int r = 0; r < 4; ++r) {
        const int row = q0 + wave * 16 + quad * 4 + r;
        O[(size_t)(b * SEQ + row) * (NH * HD) + col] = f2bf(oacc[t][r] * li[r]);
      }
    }
  }
}

extern "C" void kernel_launch(void* const* d_in, const int* in_sizes, int n_in,
                              void* d_out, int out_size, void* d_ws, size_t ws_size,
                              hipStream_t stream) {
  const float* hidden = (const float*)d_in[0];
  const float* cosb   = (const float*)d_in[1];
  const float* sinb   = (const float*)d_in[2];
  const float* Wq     = (const float*)d_in[3];
  const float* Wk     = (const float*)d_in[4];
  const float* Wv     = (const float*)d_in[5];
  const float* Wo     = (const float*)d_in[6];
  const float* qw     = (const float*)d_in[7];
  const float* kw     = (const float*)d_in[8];
  (void)in_sizes; (void)n_in; (void)out_size; (void)ws_size;

  char* ws = (char*)d_ws;
  size_t off = 0;
  auto alloc = [&](size_t n) { char* p = ws + off; off += (n + 255) & ~(size_t)255; return p; };

  unsigned short* hb    = (unsigned short*)alloc((size_t)MT * HIDDEN * 2);   // (16 MB)
  unsigned short* wqkvt = (unsigned short*)alloc((size_t)NQKV * HIDDEN * 2); // (12 MB)
  unsigned short* wot   = (unsigned short*)alloc((size_t)2048 * 2048 * 2);   // (8 MB)
  unsigned short* Qb  = (unsigned short*)alloc((size_t)MT * 2048 * 2);  // (16 MB)
  unsigned short* Kbb = (unsigned short*)alloc((size_t)MT * 512 * 2);   // (4 MB)
  unsigned short* Vtb = (unsigned short*)alloc((size_t)MT * 512 * 2);   // (4 MB)
  unsigned short* Ob  = (unsigned short*)alloc((size_t)MT * 2048 * 2);  // (16 MB)

  // fused prep: cast (8192 blocks) + weight transpose (12288 blocks)
  prep_kernel<<<20480, 256, 0, stream>>>(hidden, hb, Wq, Wk, Wv, Wo, wqkvt, wot);

  // fused QKV projection + norm/rope/V-transpose epilogue: grid 32x24 = 768 blocks
  gemm_qkv_kernel<<<dim3(MT / 128, NQKV / 128), 256, 0, stream>>>(
      hb, wqkvt, qw, kw, cosb, sinb, Qb, Kbb, Vtb);

  // paired q-tiles: 16 pairs x 32 (b,h) = 512 blocks, uniform 17 kv-tiles each
  attn_kernel<<<512, 256, 0, stream>>>(Qb, Kbb, Vtb, Ob);

  // O-projection: 32x32x16 MFMA
  gemm_bf16_kernel<<<dim3(MT / 128, 16), 256, 0, stream>>>(Ob, wot, (float*)d_out, MT, 2048, 2048);
}